// Round 1
// baseline (217.757 us; speedup 1.0000x reference)
//
#include <hip/hip_runtime.h>
#include <math.h>

#define D 196
#define NCH 64
#define NH 8
#define DHD 64
#define INNER 512
#define MLP 784
#define SEQ 65

// ---------- helpers ----------
__device__ __forceinline__ float block_reduce_sum_256(float v, float* red) {
    // 256 threads = 4 waves of 64
    for (int off = 32; off > 0; off >>= 1) v += __shfl_down(v, off, 64);
    int lane = threadIdx.x & 63, wid = threadIdx.x >> 6;
    if (lane == 0) red[wid] = v;
    __syncthreads();
    float s = red[0] + red[1] + red[2] + red[3];
    __syncthreads();
    return s;
}

// ---------- K1: conv(1x3 effective) + BN + ReLU + row mean ----------
__global__ void k_conv(const float* __restrict__ x_pe, const float* __restrict__ conv_k,
                       const float* __restrict__ bn_g, const float* __restrict__ bn_b,
                       const float* __restrict__ bn_rm, const float* __restrict__ bn_rv,
                       float* __restrict__ a, float* __restrict__ b1) {
    int ch = blockIdx.x;
    int t = threadIdx.x;
    const float* row = x_pe + ch * D;
    float km0 = conv_k[3], km1 = conv_k[4], km2 = conv_k[5];  // conv_k[1][:]
    float inv = rsqrtf(bn_rv[0] + 1e-5f);
    float g = bn_g[0], bb = bn_b[0], rm = bn_rm[0];
    float val = 0.f;
    if (t < D) {
        float l = (t > 0) ? row[t - 1] : 0.f;
        float m = row[t];
        float r = (t < D - 1) ? row[t + 1] : 0.f;
        float conv = km0 * l + km1 * m + km2 * r;
        float bn = (conv - rm) * inv * g + bb;
        val = fmaxf(bn, 0.f);
        a[ch * D + t] = val;
    }
    __shared__ float red[4];
    float tot = block_reduce_sum_256(val, red);
    if (t == 0) b1[ch] = tot / (float)D;
}

// ---------- K2: sort-based gating + FC(64->12->64) + sigmoid ----------
__global__ void k_gate(const float* __restrict__ b1, const float* __restrict__ fc_w1,
                       const float* __restrict__ fc_w2, float* __restrict__ c) {
    int i = threadIdx.x;  // 0..63
    __shared__ float sb1[NCH];
    __shared__ float sb2[NCH];
    __shared__ float hid[12];
    sb1[i] = b1[i];
    __syncthreads();
    float v = sb1[i];
    float mx = -1e30f, mn = 1e30f;
    int cle = 0, rank = 0;
    for (int j = 0; j < NCH; j++) {
        float w = sb1[j];
        mx = fmaxf(mx, w);
        mn = fminf(mn, w);
        if (w <= 0.f) cle++;
        if (w < v || (w == v && j < i)) rank++;
    }
    int middle;
    if (mx < 0.f || mn > 0.f) middle = 32;
    else if (mx <= 0.f) middle = 0;      // argmax of all-False = 0
    else middle = cle;                   // first positive in sorted order
    float b2;
    if (rank < middle) {
        float ls = (float)middle;
        b2 = v - 1.f / (1.f + powf(ls, v));
    } else {
        float le = (float)(NCH - middle);
        b2 = v + 1.f / (1.f + powf(le, -v));
    }
    sb2[i] = b2;
    __syncthreads();
    if (i < 12) {
        float s = 0.f;
        for (int j = 0; j < NCH; j++) s += sb2[j] * fc_w1[j * 12 + i];
        hid[i] = fmaxf(s, 0.f);
    }
    __syncthreads();
    float s = 0.f;
    for (int k = 0; k < 12; k++) s += hid[k] * fc_w2[k * NCH + i];
    c[i] = 1.f / (1.f + expf(-s));
}

// ---------- K3: LN1 + QKV projection ----------
__global__ void k_qkv(const float* __restrict__ x, const float* __restrict__ ln1_g,
                      const float* __restrict__ ln1_b, const float* __restrict__ w_qkv,
                      float* __restrict__ qkv) {
    int n = blockIdx.x, t = threadIdx.x;
    __shared__ float h[D];
    __shared__ float red[4];
    const float* row = x + n * D;
    float v = (t < D) ? row[t] : 0.f;
    float mean = block_reduce_sum_256(v, red) / (float)D;
    float d = (t < D) ? (v - mean) : 0.f;
    float var = block_reduce_sum_256(d * d, red) / (float)D;
    float rinv = rsqrtf(var + 1e-5f);
    if (t < D) h[t] = d * rinv * ln1_g[t] + ln1_b[t];
    __syncthreads();
    for (int rep = 0; rep < 6; rep++) {
        int col = t + rep * 256;  // 6*256 = 1536
        float acc = 0.f;
        for (int i = 0; i < D; i++) acc += h[i] * w_qkv[i * 1536 + col];
        qkv[n * 1536 + col] = acc;
    }
}

// ---------- K4: attention, one block per (query n, head h) ----------
__global__ void k_attn(const float* __restrict__ qkv, float* __restrict__ o) {
    int n = blockIdx.x, hh = blockIdx.y;
    int t = threadIdx.x;  // 0..63
    __shared__ float q[DHD];
    __shared__ float p[SEQ];
    q[t] = qkv[n * 1536 + hh * DHD + t];
    __syncthreads();
    const float scale = 0.125f;  // 64^-0.5
    for (int m = t; m < SEQ; m += 64) {
        const float* krow = qkv + m * 1536 + 512 + hh * DHD;
        float s = 0.f;
        for (int dd = 0; dd < DHD; dd++) s += q[dd] * krow[dd];
        p[m] = s * scale;
    }
    __syncthreads();
    float mx = -1e30f;
    for (int m = 0; m < SEQ; m++) mx = fmaxf(mx, p[m]);
    __syncthreads();
    for (int m = t; m < SEQ; m += 64) p[m] = expf(p[m] - mx);
    __syncthreads();
    float sum = 0.f;
    for (int m = 0; m < SEQ; m++) sum += p[m];
    float rs = 1.f / sum;
    float acc = 0.f;
    for (int m = 0; m < SEQ; m++) acc += p[m] * qkv[m * 1536 + 1024 + hh * DHD + t];
    o[n * INNER + hh * DHD + t] = acc * rs;
}

// ---------- K5: out-projection + residuals (x + x_att) ----------
__global__ void k_outproj(const float* __restrict__ o, const float* __restrict__ w_out,
                          const float* __restrict__ b_out, const float* __restrict__ x,
                          const float* __restrict__ a, const float* __restrict__ c,
                          const float* __restrict__ tokens, float* __restrict__ x2) {
    int n = blockIdx.x, t = threadIdx.x;  // 256 threads
    __shared__ float so[INNER];
    so[t] = o[n * INNER + t];
    so[t + 256] = o[n * INNER + t + 256];
    __syncthreads();
    if (t < D) {
        float acc = 0.f;
        for (int i = 0; i < INNER; i++) acc += so[i] * w_out[i * D + t];
        float att = (n < NCH) ? a[n * D + t] * c[n] : tokens[t];
        x2[n * D + t] = acc + b_out[t] + x[n * D + t] + att;
    }
}

// ---------- K6: LN2 + FF1 + exact GELU ----------
__global__ void k_ff1(const float* __restrict__ x2, const float* __restrict__ ln2_g,
                      const float* __restrict__ ln2_b, const float* __restrict__ ff_w1,
                      const float* __restrict__ ff_b1, float* __restrict__ tb) {
    int n = blockIdx.x, t = threadIdx.x;
    __shared__ float h[D];
    __shared__ float red[4];
    const float* row = x2 + n * D;
    float v = (t < D) ? row[t] : 0.f;
    float mean = block_reduce_sum_256(v, red) / (float)D;
    float d = (t < D) ? (v - mean) : 0.f;
    float var = block_reduce_sum_256(d * d, red) / (float)D;
    float rinv = rsqrtf(var + 1e-5f);
    if (t < D) h[t] = d * rinv * ln2_g[t] + ln2_b[t];
    __syncthreads();
    for (int col = t; col < MLP; col += 256) {
        float acc = ff_b1[col];
        for (int i = 0; i < D; i++) acc += h[i] * ff_w1[i * MLP + col];
        float g = 0.5f * acc * (1.f + erff(acc * 0.70710678118f));
        tb[n * MLP + col] = g;
    }
}

// ---------- K7: FF2 + residual -> out ----------
__global__ void k_ff2(const float* __restrict__ tb, const float* __restrict__ ff_w2,
                      const float* __restrict__ ff_b2, const float* __restrict__ x2,
                      float* __restrict__ out) {
    int n = blockIdx.x, t = threadIdx.x;
    __shared__ float st[MLP];
    for (int k = t; k < MLP; k += 256) st[k] = tb[n * MLP + k];
    __syncthreads();
    if (t < D) {
        float acc = 0.f;
        for (int i = 0; i < MLP; i++) acc += st[i] * ff_w2[i * D + t];
        out[n * D + t] = acc + ff_b2[t] + x2[n * D + t];
    }
}

extern "C" void kernel_launch(void* const* d_in, const int* in_sizes, int n_in,
                              void* d_out, int out_size, void* d_ws, size_t ws_size,
                              hipStream_t stream) {
    const float* x      = (const float*)d_in[0];
    const float* tokens = (const float*)d_in[1];
    const float* x_pe   = (const float*)d_in[2];
    const float* conv_k = (const float*)d_in[3];
    const float* bn_g   = (const float*)d_in[4];
    const float* bn_b   = (const float*)d_in[5];
    const float* bn_rm  = (const float*)d_in[6];
    const float* bn_rv  = (const float*)d_in[7];
    const float* fc_w1  = (const float*)d_in[8];
    const float* fc_w2  = (const float*)d_in[9];
    const float* ln1_g  = (const float*)d_in[10];
    const float* ln1_b  = (const float*)d_in[11];
    const float* ln2_g  = (const float*)d_in[12];
    const float* ln2_b  = (const float*)d_in[13];
    const float* w_qkv  = (const float*)d_in[14];
    const float* w_out  = (const float*)d_in[15];
    const float* b_out  = (const float*)d_in[16];
    const float* ff_w1  = (const float*)d_in[17];
    const float* ff_b1  = (const float*)d_in[18];
    const float* ff_w2  = (const float*)d_in[19];
    const float* ff_b2  = (const float*)d_in[20];
    float* out = (float*)d_out;

    float* ws  = (float*)d_ws;
    float* a    = ws;             // 64*196   = 12544
    float* b1   = ws + 12544;     // 64
    float* cc   = ws + 12608;     // 64
    float* qkv  = ws + 12672;     // 65*1536  = 99840
    float* o    = ws + 112512;    // 65*512   = 33280
    float* x2   = ws + 145792;    // 65*196   = 12740
    float* tb   = ws + 158532;    // 65*784   = 50960  (end: 209492 floats)

    k_conv<<<NCH, 256, 0, stream>>>(x_pe, conv_k, bn_g, bn_b, bn_rm, bn_rv, a, b1);
    k_gate<<<1, 64, 0, stream>>>(b1, fc_w1, fc_w2, cc);
    k_qkv<<<SEQ, 256, 0, stream>>>(x, ln1_g, ln1_b, w_qkv, qkv);
    k_attn<<<dim3(SEQ, NH), 64, 0, stream>>>(qkv, o);
    k_outproj<<<SEQ, 256, 0, stream>>>(o, w_out, b_out, x, a, cc, tokens, x2);
    k_ff1<<<SEQ, 256, 0, stream>>>(x2, ln2_g, ln2_b, ff_w1, ff_b1, tb);
    k_ff2<<<SEQ, 256, 0, stream>>>(tb, ff_w2, ff_b2, x2, out);
}

// Round 2
// 191.345 us; speedup vs baseline: 1.1380x; 1.1380x over previous
//
#include <hip/hip_runtime.h>
#include <math.h>

#define D 196
#define NCH 64
#define NH 8
#define DHD 64
#define INNER 512
#define MLP 784
#define SEQ 65

// ---------- helpers ----------
__device__ __forceinline__ float block_reduce_sum_256(float v, float* red) {
    for (int off = 32; off > 0; off >>= 1) v += __shfl_down(v, off, 64);
    int lane = threadIdx.x & 63, wid = threadIdx.x >> 6;
    if (lane == 0) red[wid] = v;
    __syncthreads();
    float s = red[0] + red[1] + red[2] + red[3];
    __syncthreads();
    return s;
}

// ---------- K1: fused conv+BN+ReLU + row means + sort gating + FC + sigmoid (1 block) ----------
__global__ void k_convgate(const float* __restrict__ x_pe, const float* __restrict__ conv_k,
                           const float* __restrict__ bn_g, const float* __restrict__ bn_b,
                           const float* __restrict__ bn_rm, const float* __restrict__ bn_rv,
                           const float* __restrict__ fc_w1, const float* __restrict__ fc_w2,
                           float* __restrict__ a, float* __restrict__ c) {
    int t = threadIdx.x;  // 256 threads
    __shared__ float s_a[NCH * D];
    __shared__ float sb1[NCH];
    __shared__ float sb2[NCH];
    __shared__ float hid[12];
    float km0 = conv_k[3], km1 = conv_k[4], km2 = conv_k[5];
    float inv = rsqrtf(bn_rv[0] + 1e-5f);
    float g = bn_g[0], bb = bn_b[0], rm = bn_rm[0];
    for (int idx = t; idx < NCH * D; idx += 256) {
        int ch = idx / D, pos = idx - ch * D;
        const float* row = x_pe + ch * D;
        float l = (pos > 0) ? row[pos - 1] : 0.f;
        float m = row[pos];
        float r = (pos < D - 1) ? row[pos + 1] : 0.f;
        float conv = km0 * l + km1 * m + km2 * r;
        float bn = (conv - rm) * inv * g + bb;
        float val = fmaxf(bn, 0.f);
        a[idx] = val;
        s_a[idx] = val;
    }
    __syncthreads();
    if (t < NCH) {
        float s = 0.f;
        for (int p = 0; p < D; p++) s += s_a[t * D + p];
        sb1[t] = s / (float)D;
    }
    __syncthreads();
    if (t < NCH) {
        float v = sb1[t];
        float mx = -1e30f, mn = 1e30f;
        int cle = 0, rank = 0;
        for (int j = 0; j < NCH; j++) {
            float w = sb1[j];
            mx = fmaxf(mx, w);
            mn = fminf(mn, w);
            if (w <= 0.f) cle++;
            if (w < v || (w == v && j < t)) rank++;
        }
        int middle;
        if (mx < 0.f || mn > 0.f) middle = 32;
        else if (mx <= 0.f) middle = 0;
        else middle = cle;
        float b2;
        if (rank < middle) {
            float ls = (float)middle;
            b2 = v - 1.f / (1.f + powf(ls, v));
        } else {
            float le = (float)(NCH - middle);
            b2 = v + 1.f / (1.f + powf(le, -v));
        }
        sb2[t] = b2;
    }
    __syncthreads();
    if (t < 12) {
        float s = 0.f;
        for (int j = 0; j < NCH; j++) s += sb2[j] * fc_w1[j * 12 + t];
        hid[t] = fmaxf(s, 0.f);
    }
    __syncthreads();
    if (t < NCH) {
        float s = 0.f;
        for (int k = 0; k < 12; k++) s += hid[k] * fc_w2[k * NCH + t];
        c[t] = 1.f / (1.f + expf(-s));
    }
}

// ---------- K2: LN1 + QKV projection, grid (65, 6) ----------
__global__ void k_qkv(const float* __restrict__ x, const float* __restrict__ ln1_g,
                      const float* __restrict__ ln1_b, const float* __restrict__ w_qkv,
                      float* __restrict__ qkv) {
    int n = blockIdx.x, rep = blockIdx.y, t = threadIdx.x;
    __shared__ float h[D];
    __shared__ float red[4];
    const float* row = x + n * D;
    float v = (t < D) ? row[t] : 0.f;
    float mean = block_reduce_sum_256(v, red) / (float)D;
    float d = (t < D) ? (v - mean) : 0.f;
    float var = block_reduce_sum_256(d * d, red) / (float)D;
    float rinv = rsqrtf(var + 1e-5f);
    if (t < D) h[t] = d * rinv * ln1_g[t] + ln1_b[t];
    __syncthreads();
    int col = rep * 256 + t;
    const float* wp = w_qkv + col;
    float acc = 0.f;
#pragma unroll 4
    for (int i = 0; i < D; i++) acc += h[i] * wp[i * 1536];
    qkv[n * 1536 + col] = acc;
}

// ---------- K3: attention, one wave per (query n, head h) ----------
__global__ void k_attn(const float* __restrict__ qkv, float* __restrict__ o) {
    int n = blockIdx.x, hh = blockIdx.y;
    int t = threadIdx.x;  // 0..63
    __shared__ float q[DHD];
    __shared__ float p[SEQ];
    q[t] = qkv[n * 1536 + hh * DHD + t];
    __syncthreads();
    const float scale = 0.125f;
    for (int m = t; m < SEQ; m += 64) {
        const float* krow = qkv + m * 1536 + 512 + hh * DHD;
        float s = 0.f;
#pragma unroll 8
        for (int dd = 0; dd < DHD; dd++) s += q[dd] * krow[dd];
        p[m] = s * scale;
    }
    __syncthreads();
    float mx = -1e30f;
    for (int m = 0; m < SEQ; m++) mx = fmaxf(mx, p[m]);
    __syncthreads();
    for (int m = t; m < SEQ; m += 64) p[m] = expf(p[m] - mx);
    __syncthreads();
    float sum = 0.f;
    for (int m = 0; m < SEQ; m++) sum += p[m];
    float rs = 1.f / sum;
    float acc = 0.f;
    for (int m = 0; m < SEQ; m++) acc += p[m] * qkv[m * 1536 + 1024 + hh * DHD + t];
    o[n * INNER + hh * DHD + t] = acc * rs;
}

// ---------- K4: x2 = b_out + x + x_att (init for split-K atomics) ----------
__global__ void k_x2init(const float* __restrict__ x, const float* __restrict__ b_out,
                         const float* __restrict__ a, const float* __restrict__ c,
                         const float* __restrict__ tokens, float* __restrict__ x2) {
    int n = blockIdx.x, t = threadIdx.x;
    if (t < D) {
        float att = (n < NCH) ? a[n * D + t] * c[n] : tokens[t];
        x2[n * D + t] = b_out[t] + x[n * D + t] + att;
    }
}

// ---------- K5: out-projection split-K, grid (65, 4), atomicAdd into x2 ----------
__global__ void k_outproj(const float* __restrict__ o, const float* __restrict__ w_out,
                          float* __restrict__ x2) {
    int n = blockIdx.x, kc = blockIdx.y, t = threadIdx.x;
    __shared__ float so[128];
    if (t < 128) so[t] = o[n * INNER + kc * 128 + t];
    __syncthreads();
    if (t < D) {
        const float* wp = w_out + kc * 128 * D + t;
        float acc = 0.f;
#pragma unroll 4
        for (int i = 0; i < 128; i++) acc += so[i] * wp[i * D];
        atomicAdd(&x2[n * D + t], acc);
    }
}

// ---------- K6: LN2 + FF1 + exact GELU, grid (65, 4) ----------
__global__ void k_ff1(const float* __restrict__ x2, const float* __restrict__ ln2_g,
                      const float* __restrict__ ln2_b, const float* __restrict__ ff_w1,
                      const float* __restrict__ ff_b1, float* __restrict__ tb) {
    int n = blockIdx.x, g = blockIdx.y, t = threadIdx.x;
    __shared__ float h[D];
    __shared__ float red[4];
    const float* row = x2 + n * D;
    float v = (t < D) ? row[t] : 0.f;
    float mean = block_reduce_sum_256(v, red) / (float)D;
    float d = (t < D) ? (v - mean) : 0.f;
    float var = block_reduce_sum_256(d * d, red) / (float)D;
    float rinv = rsqrtf(var + 1e-5f);
    if (t < D) h[t] = d * rinv * ln2_g[t] + ln2_b[t];
    __syncthreads();
    if (t < D) {
        int col = g * D + t;  // 4*196 = 784
        const float* wp = ff_w1 + col;
        float acc = ff_b1[col];
#pragma unroll 4
        for (int i = 0; i < D; i++) acc += h[i] * wp[i * MLP];
        float gl = 0.5f * acc * (1.f + erff(acc * 0.70710678118f));
        tb[n * MLP + col] = gl;
    }
}

// ---------- K7: out = ff_b2 + x2 (init for split-K atomics) ----------
__global__ void k_outinit(const float* __restrict__ x2, const float* __restrict__ ff_b2,
                          float* __restrict__ out) {
    int n = blockIdx.x, t = threadIdx.x;
    if (t < D) out[n * D + t] = ff_b2[t] + x2[n * D + t];
}

// ---------- K8: FF2 split-K, grid (65, 4), atomicAdd into out ----------
__global__ void k_ff2(const float* __restrict__ tb, const float* __restrict__ ff_w2,
                      float* __restrict__ out) {
    int n = blockIdx.x, kc = blockIdx.y, t = threadIdx.x;
    __shared__ float st[D];
    if (t < D) st[t] = tb[n * MLP + kc * D + t];
    __syncthreads();
    if (t < D) {
        const float* wp = ff_w2 + kc * D * D + t;
        float acc = 0.f;
#pragma unroll 4
        for (int i = 0; i < D; i++) acc += st[i] * wp[i * D];
        atomicAdd(&out[n * D + t], acc);
    }
}

extern "C" void kernel_launch(void* const* d_in, const int* in_sizes, int n_in,
                              void* d_out, int out_size, void* d_ws, size_t ws_size,
                              hipStream_t stream) {
    const float* x      = (const float*)d_in[0];
    const float* tokens = (const float*)d_in[1];
    const float* x_pe   = (const float*)d_in[2];
    const float* conv_k = (const float*)d_in[3];
    const float* bn_g   = (const float*)d_in[4];
    const float* bn_b   = (const float*)d_in[5];
    const float* bn_rm  = (const float*)d_in[6];
    const float* bn_rv  = (const float*)d_in[7];
    const float* fc_w1  = (const float*)d_in[8];
    const float* fc_w2  = (const float*)d_in[9];
    const float* ln1_g  = (const float*)d_in[10];
    const float* ln1_b  = (const float*)d_in[11];
    const float* ln2_g  = (const float*)d_in[12];
    const float* ln2_b  = (const float*)d_in[13];
    const float* w_qkv  = (const float*)d_in[14];
    const float* w_out  = (const float*)d_in[15];
    const float* b_out  = (const float*)d_in[16];
    const float* ff_w1  = (const float*)d_in[17];
    const float* ff_b1  = (const float*)d_in[18];
    const float* ff_w2  = (const float*)d_in[19];
    const float* ff_b2  = (const float*)d_in[20];
    float* out = (float*)d_out;

    float* ws  = (float*)d_ws;
    float* a    = ws;             // 64*196   = 12544
    float* cc   = ws + 12544;     // 64
    float* qkv  = ws + 12608;     // 65*1536  = 99840
    float* o    = ws + 112448;    // 65*512   = 33280
    float* x2   = ws + 145728;    // 65*196   = 12740
    float* tb   = ws + 158468;    // 65*784   = 50960

    k_convgate<<<1, 256, 0, stream>>>(x_pe, conv_k, bn_g, bn_b, bn_rm, bn_rv,
                                      fc_w1, fc_w2, a, cc);
    k_qkv<<<dim3(SEQ, 6), 256, 0, stream>>>(x, ln1_g, ln1_b, w_qkv, qkv);
    k_attn<<<dim3(SEQ, NH), 64, 0, stream>>>(qkv, o);
    k_x2init<<<SEQ, 256, 0, stream>>>(x, b_out, a, cc, tokens, x2);
    k_outproj<<<dim3(SEQ, 4), 256, 0, stream>>>(o, w_out, x2);
    k_ff1<<<dim3(SEQ, 4), 256, 0, stream>>>(x2, ln2_g, ln2_b, ff_w1, ff_b1, tb);
    k_outinit<<<SEQ, 256, 0, stream>>>(x2, ff_b2, out);
    k_ff2<<<dim3(SEQ, 4), 256, 0, stream>>>(tb, ff_w2, out);
}